// Round 9
// baseline (511.192 us; speedup 1.0000x reference)
//
#include <hip/hip_runtime.h>
#include <hip/hip_bf16.h>
#include <hip/hip_fp16.h>

// Problem constants (match reference)
static constexpr int CH     = 128;   // IN_CH == HID
static constexpr int NCLS   = 32;
static constexpr int NGRAPH = 256;

// Bucketed CSR build: buckets are 512-node ranges (bucket = dst >> 9).
static constexpr int BSHIFT = 9;
static constexpr int BW     = 1 << BSHIFT;   // 512 nodes per bucket
static constexpr int MAXB   = 256;

typedef _Float16 half8 __attribute__((ext_vector_type(8)));
typedef float    f32x4 __attribute__((ext_vector_type(4)));

// ---------------------------------------------------------------------------
// 1) bucket histogram (LDS-aggregated)
// ---------------------------------------------------------------------------
__global__ __launch_bounds__(256) void k_hist(const int* __restrict__ dst,
                                              int* __restrict__ gbcnt, int E) {
  __shared__ int h[MAXB];
  int t = threadIdx.x;
  h[t] = 0;
  __syncthreads();
  for (int i = blockIdx.x * 256 + t; i < E; i += gridDim.x * 256)
    atomicAdd(&h[dst[i] >> BSHIFT], 1);
  __syncthreads();
  if (h[t]) atomicAdd(&gbcnt[t], h[t]);
}

// ---------------------------------------------------------------------------
// 2) scan bucket counts -> ebase[257]; init bucket cursors
// ---------------------------------------------------------------------------
__global__ __launch_bounds__(256) void k_bscan(const int* __restrict__ gbcnt,
                                               int* __restrict__ ebase,
                                               int* __restrict__ gcur) {
  __shared__ int s[MAXB];
  int t = threadIdx.x;
  int v0 = gbcnt[t];
  s[t] = v0;
  __syncthreads();
  for (int st = 1; st < MAXB; st <<= 1) {
    int v = (t >= st) ? s[t - st] : 0;
    __syncthreads();
    s[t] += v;
    __syncthreads();
  }
  int ex = s[t] - v0;
  ebase[t] = ex;
  gcur[t]  = ex;
  if (t == MAXB - 1) ebase[MAXB] = s[t];
}

// ---------------------------------------------------------------------------
// 3) scatter packed edges into bucket-ordered array.
//    pack = (dstlo << 17) | src   (dstlo < 512 -> 9 bits; src < 2^17)
// ---------------------------------------------------------------------------
__global__ __launch_bounds__(1024) void k_scatter(
    const int* __restrict__ src, const int* __restrict__ dst,
    int* __restrict__ gcur, int* __restrict__ ebuf, int E) {
  __shared__ int bcnt[MAXB];
  __shared__ int bbase[MAXB];
  int t = threadIdx.x;
  if (t < MAXB) bcnt[t] = 0;
  __syncthreads();
  int base = blockIdx.x * 8192;
  int s_[8], d_[8], r_[8];
  #pragma unroll
  for (int j = 0; j < 8; ++j) {
    int i = base + j * 1024 + t;
    if (i < E) {
      s_[j] = src[i];
      d_[j] = dst[i];
      r_[j] = atomicAdd(&bcnt[d_[j] >> BSHIFT], 1);
    }
  }
  __syncthreads();
  if (t < MAXB && bcnt[t]) bbase[t] = atomicAdd(&gcur[t], bcnt[t]);
  __syncthreads();
  #pragma unroll
  for (int j = 0; j < 8; ++j) {
    int i = base + j * 1024 + t;
    if (i < E) {
      int b = d_[j] >> BSHIFT;
      int p = ((d_[j] & (BW - 1)) << 17) | s_[j];
      ebuf[bbase[b] + r_[j]] = p;
    }
  }
}

// ---------------------------------------------------------------------------
// 4) per-bucket CSR build (packed edges)
// ---------------------------------------------------------------------------
__global__ __launch_bounds__(1024) void k_build(
    const int* __restrict__ ebuf, const int* __restrict__ ebase,
    int* __restrict__ offs, float* __restrict__ dinv,
    int* __restrict__ csr, int N, int E, int NBUCK) {
  __shared__ int sdeg[BW];
  __shared__ int sscan[BW];
  int b = blockIdx.x;
  int t = threadIdx.x;
  int lo = b << BSHIFT;
  int e0 = ebase[b], e1 = ebase[b + 1];

  if (t < BW) sdeg[t] = 0;
  __syncthreads();
  for (int e = e0 + t; e < e1; e += 1024)
    atomicAdd(&sdeg[ebuf[e] >> 17], 1);
  __syncthreads();
  if (t < BW) sscan[t] = sdeg[t];
  __syncthreads();
  for (int st = 1; st < BW; st <<= 1) {
    int v = (t < BW && t >= st) ? sscan[t - st] : 0;
    __syncthreads();
    if (t < BW) sscan[t] += v;
    __syncthreads();
  }
  if (t < BW) {
    int ex = e0 + sscan[t] - sdeg[t];
    int n = lo + t;
    if (n < N) {
      offs[n] = ex;
      dinv[n] = 1.0f / sqrtf((float)(sdeg[t] + 1));
    }
    sscan[t] = ex;
  }
  if (b == NBUCK - 1 && t == 0) offs[N] = E;
  __syncthreads();
  for (int e = e0 + t; e < e1; e += 1024) {
    int p = ebuf[e];
    int pos = atomicAdd(&sscan[p >> 17], 1);
    csr[pos] = p & 0x1FFFF;
  }
}

// ---------------------------------------------------------------------------
// 5) one-shot W1,W2 -> fp16 transpose: WhT[n][k] = W[k][n]
// ---------------------------------------------------------------------------
__global__ __launch_bounds__(256) void k_wt(const float* __restrict__ W1,
                                            const float* __restrict__ W2,
                                            _Float16* __restrict__ WhT1,
                                            _Float16* __restrict__ WhT2) {
  int i = blockIdx.x * 256 + threadIdx.x;   // grid 128 x 256 = 32768
  const float* W = (i < CH * CH) ? W1 : W2;
  _Float16* T   = (i < CH * CH) ? WhT1 : WhT2;
  int j = i & (CH * CH - 1);
  int k = j >> 7, n = j & 127;
  T[n * CH + k] = (_Float16)W[j];
}

// ---------------------------------------------------------------------------
// MFMA GEMM, register-resident W. 256 threads = 4 waves, tile 128 rows.
// W^T fragments (32KB, identical for every block -> L1/L2-hot) live in 128
// VGPRs/lane; only A goes through LDS. K=128 single shot.
// ---------------------------------------------------------------------------
__device__ __forceinline__ void gemm_core_regW(
    const _Float16 (*As)[136], const half8 wf[4][8],
    const float* __restrict__ dinv, __half* __restrict__ C,
    int row0, int M, int tid) {
  int lane = tid & 63, wave = tid >> 6;
  int quad = lane >> 4, sub = lane & 15;
  int m0 = wave * 32;

  f32x4 acc[2][8];
  #pragma unroll
  for (int i = 0; i < 2; ++i)
    #pragma unroll
    for (int j = 0; j < 8; ++j) acc[i][j] = (f32x4){0.f, 0.f, 0.f, 0.f};

  #pragma unroll
  for (int kc = 0; kc < 4; ++kc) {
    int ko = kc * 32 + quad * 8;
    half8 a0 = *(const half8*)&As[m0 + sub][ko];
    half8 a1 = *(const half8*)&As[m0 + 16 + sub][ko];
    #pragma unroll
    for (int nt = 0; nt < 8; ++nt) {
      acc[0][nt] = __builtin_amdgcn_mfma_f32_16x16x32_f16(a0, wf[kc][nt], acc[0][nt], 0, 0, 0);
      acc[1][nt] = __builtin_amdgcn_mfma_f32_16x16x32_f16(a1, wf[kc][nt], acc[1][nt], 0, 0, 0);
    }
  }
  #pragma unroll
  for (int mt = 0; mt < 2; ++mt) {
    #pragma unroll
    for (int r = 0; r < 4; ++r) {
      int row = row0 + m0 + mt * 16 + quad * 4 + r;
      if (row < M) {
        float d = dinv[row];
        #pragma unroll
        for (int nt = 0; nt < 8; ++nt) {
          int col = nt * 16 + sub;
          C[(size_t)row * CH + col] = __float2half(acc[mt][nt][r] * d);
        }
      }
    }
  }
}

__device__ __forceinline__ void load_wfrag(const _Float16* __restrict__ WhT,
                                           half8 wf[4][8], int tid) {
  int lane = tid & 63;
  int quad = lane >> 4, sub = lane & 15;
  #pragma unroll
  for (int kc = 0; kc < 4; ++kc)
    #pragma unroll
    for (int nt = 0; nt < 8; ++nt)
      wf[kc][nt] = *(const half8*)(WhT + (size_t)(nt * 16 + sub) * CH + kc * 32 + quad * 8);
}

// A input fp32 (layer 1: x)
__global__ __launch_bounds__(256) void k_gemm_f32(
    const float* __restrict__ A, const _Float16* __restrict__ WhT,
    const float* __restrict__ dinv, __half* __restrict__ C, int M) {
  __shared__ _Float16 As[128][136];
  int tid = threadIdx.x;
  int row0 = blockIdx.x * 128;
  half8 wf[4][8];
  load_wfrag(WhT, wf, tid);          // in flight during A staging
  #pragma unroll
  for (int l = 0; l < 16; ++l) {
    int idx = tid + l * 256;         // 0..4095 float4 slots
    int r = idx >> 5, c4 = (idx & 31) << 2;
    int rr = row0 + r; if (rr >= M) rr = M - 1;
    float4 v = *(const float4*)(A + (size_t)rr * CH + c4);
    As[r][c4 + 0] = (_Float16)v.x; As[r][c4 + 1] = (_Float16)v.y;
    As[r][c4 + 2] = (_Float16)v.z; As[r][c4 + 3] = (_Float16)v.w;
  }
  __syncthreads();
  gemm_core_regW(As, wf, dinv, C, row0, M, tid);
}

// A input fp16 (layer 2: h)
__global__ __launch_bounds__(256) void k_gemm_f16(
    const _Float16* __restrict__ A, const _Float16* __restrict__ WhT,
    const float* __restrict__ dinv, __half* __restrict__ C, int M) {
  __shared__ _Float16 As[128][136];
  int tid = threadIdx.x;
  int row0 = blockIdx.x * 128;
  half8 wf[4][8];
  load_wfrag(WhT, wf, tid);
  #pragma unroll
  for (int l = 0; l < 8; ++l) {
    int idx = tid + l * 256;         // 0..2047 half8 chunks
    int r = idx >> 4, c8 = (idx & 15) << 3;
    int rr = row0 + r; if (rr >= M) rr = M - 1;
    *(half8*)&As[r][c8] = *(const half8*)(A + (size_t)rr * CH + c8);
  }
  __syncthreads();
  gemm_core_regW(As, wf, dinv, C, row0, M, tid);
}

// ---------------------------------------------------------------------------
// Aggregation (pull, CSR): out fp16
// ---------------------------------------------------------------------------
__global__ __launch_bounds__(256) void k_agg(
    const __half* __restrict__ xs, const int* __restrict__ csr,
    const int* __restrict__ offs, const float* __restrict__ dinv,
    const float* __restrict__ bias, __half* __restrict__ out, int N) {
  int node = blockIdx.x * 4 + (threadIdx.x >> 6);
  int lane = threadIdx.x & 63;
  if (node >= N) return;
  int beg = offs[node], end = offs[node + 1];
  const __half2* base = (const __half2*)xs;
  float2 self = __half22float2(base[(size_t)node * 64 + lane]);
  float ax = self.x, ay = self.y;
  float bx2 = 0.f, by2 = 0.f;
  int e = beg;
  for (; e + 3 < end; e += 4) {
    int s0 = csr[e], s1 = csr[e + 1], s2 = csr[e + 2], s3 = csr[e + 3];
    float2 v0 = __half22float2(base[(size_t)s0 * 64 + lane]);
    float2 v1 = __half22float2(base[(size_t)s1 * 64 + lane]);
    float2 v2 = __half22float2(base[(size_t)s2 * 64 + lane]);
    float2 v3 = __half22float2(base[(size_t)s3 * 64 + lane]);
    ax += v0.x + v2.x; ay += v0.y + v2.y;
    bx2 += v1.x + v3.x; by2 += v1.y + v3.y;
  }
  for (; e < end; ++e) {
    int s = csr[e];
    float2 v = __half22float2(base[(size_t)s * 64 + lane]);
    ax += v.x; ay += v.y;
  }
  ax += bx2; ay += by2;
  float d = dinv[node];
  float rx = fmaf(ax, d, bias[2 * lane]);
  float ry = fmaf(ay, d, bias[2 * lane + 1]);
  ((__half2*)out)[(size_t)node * 64 + lane] =
      __floats2half2_rn(fmaxf(rx, 0.f), fmaxf(ry, 0.f));
}

// ---------------------------------------------------------------------------
// Pool + graph boundaries (batch sorted). Boundary pass costs ~1 iter/thread.
// ---------------------------------------------------------------------------
__global__ __launch_bounds__(128) void k_pool(
    const __half* __restrict__ h, const int* __restrict__ batch,
    float* __restrict__ gsum, int* __restrict__ gstart,
    int* __restrict__ gend, int N) {
  int ch = threadIdx.x;
  int n0 = blockIdx.x * 128;
  int n1 = n0 + 128; if (n1 > N) n1 = N;
  if (n0 >= N) return;
  // run boundaries (no atomics; gstart/gend pre-zeroed for empty graphs)
  for (int n = n0 + ch; n < n1; n += 128) {
    int g = batch[n];
    if (n == 0 || batch[n - 1] != g) gstart[g] = n;
    if (n == N - 1 || batch[n + 1] != g) gend[g] = n + 1;
  }
  float acc = 0.f;
  int curg = batch[n0];
  for (int n = n0; n < n1; ++n) {
    int g = batch[n];
    if (g != curg) {
      atomicAdd(&gsum[curg * CH + ch], acc);
      acc = 0.f; curg = g;
    }
    acc += __half2float(h[(size_t)n * CH + ch]);
  }
  atomicAdd(&gsum[curg * CH + ch], acc);
}

// ---------------------------------------------------------------------------
// FC
// ---------------------------------------------------------------------------
__global__ __launch_bounds__(64) void k_fc(
    const float* __restrict__ gsum, const int* __restrict__ gstart,
    const int* __restrict__ gend, const float* __restrict__ Wfc,
    const float* __restrict__ bfc, float* __restrict__ outp) {
  int g = blockIdx.x;
  int j = threadIdx.x;
  if (j >= NCLS) return;
  int cnt = gend[g] - gstart[g];
  float invc = 1.0f / fmaxf((float)cnt, 1.0f);
  float acc = 0.0f;
  for (int c = 0; c < CH; ++c)
    acc = fmaf(gsum[g * CH + c], Wfc[c * NCLS + j], acc);
  outp[g * NCLS + j] = fmaf(acc, invc, bfc[j]);
}

// ---------------------------------------------------------------------------
extern "C" void kernel_launch(void* const* d_in, const int* in_sizes, int n_in,
                              void* d_out, int out_size, void* d_ws, size_t ws_size,
                              hipStream_t stream) {
  const float* x    = (const float*)d_in[0];
  const int*   ei   = (const int*)d_in[1];
  const int*   batch= (const int*)d_in[2];
  const float* W1   = (const float*)d_in[3];
  const float* b1   = (const float*)d_in[4];
  const float* W2   = (const float*)d_in[5];
  const float* b2   = (const float*)d_in[6];
  const float* Wfc  = (const float*)d_in[7];
  const float* bfc  = (const float*)d_in[8];
  float* outp = (float*)d_out;

  const int N = in_sizes[0] / CH;       // 100000
  const int E = in_sizes[1] / 2;        // 3200000
  const int* src = ei;
  const int* dst = ei + E;
  const int NBUCK = (N + BW - 1) >> BSHIFT;   // 196

  // Workspace carve (256B aligned). The first four buffers are contiguous
  // and zero-initialized with ONE memset (sizes are multiples of 256B).
  char* w = (char*)d_ws;
  size_t o = 0;
  auto carve = [&](size_t bytes) -> void* {
    o = (o + 255) & ~(size_t)255;
    void* p = w + o;
    o += bytes;
    return p;
  };
  int*      gbcnt  = (int*)     carve(MAXB * 4);                 // zeroed
  float*    gsum   = (float*)   carve((size_t)NGRAPH * CH * 4);  // zeroed
  int*      gstart = (int*)     carve((size_t)NGRAPH * 4);       // zeroed
  int*      gend   = (int*)     carve((size_t)NGRAPH * 4);       // zeroed
  size_t zbytes = o;
  int*      offs   = (int*)     carve((size_t)(N + 1) * 4);
  int*      ebase  = (int*)     carve((MAXB + 1) * 4);
  int*      gcur   = (int*)     carve(MAXB * 4);
  int*      csr    = (int*)     carve((size_t)E * 4);
  float*    dinv   = (float*)   carve((size_t)N * 4);
  _Float16* WhT1   = (_Float16*)carve((size_t)CH * CH * 2);
  _Float16* WhT2   = (_Float16*)carve((size_t)CH * CH * 2);
  __half*   xsbuf  = (__half*)  carve((size_t)N * CH * 2);  // fp16 gather buffer
  __half*   hbuf   = (__half*)  carve((size_t)N * CH * 2);  // fp16 h
  (void)ws_size;

  // ebuf (packed edges) aliases hbuf: needs E*4 = 12.8MB <= 25.6MB
  int* ebuf = (int*)hbuf;

  (void)hipMemsetAsync(gbcnt, 0, zbytes, stream);

  // CSR build (bucketed counting sort) + weight transposes
  k_wt     <<<128, 256, 0, stream>>>(W1, W2, WhT1, WhT2);
  k_hist   <<<512, 256, 0, stream>>>(dst, gbcnt, E);
  k_bscan  <<<1, MAXB, 0, stream>>>(gbcnt, ebase, gcur);
  k_scatter<<<(E + 8191) / 8192, 1024, 0, stream>>>(src, dst, gcur, ebuf, E);
  k_build  <<<NBUCK, 1024, 0, stream>>>(ebuf, ebase, offs, dinv, csr, N, E, NBUCK);

  const int GB = (N + 127) / 128;
  const int AB = (N + 3) / 4;

  // Layer 1: xs = fp16((x@W1)*dinv) ; h = fp16(relu(agg(xs)*dinv + b1))
  k_gemm_f32<<<GB, 256, 0, stream>>>(x, WhT1, dinv, xsbuf, N);
  k_agg<<<AB, 256, 0, stream>>>(xsbuf, csr, offs, dinv, b1, hbuf, N);
  // Layer 2
  k_gemm_f16<<<GB, 256, 0, stream>>>((const _Float16*)hbuf, WhT2, dinv, xsbuf, N);
  k_agg<<<AB, 256, 0, stream>>>(xsbuf, csr, offs, dinv, b2, hbuf, N);

  // Pool (+ boundaries) + FC
  k_pool<<<GB, 128, 0, stream>>>(hbuf, batch, gsum, gstart, gend, N);
  k_fc<<<NGRAPH, 64, 0, stream>>>(gsum, gstart, gend, Wfc, bfc, outp);
  (void)out_size; (void)n_in;
}

// Round 10
// 475.722 us; speedup vs baseline: 1.0746x; 1.0746x over previous
//
#include <hip/hip_runtime.h>
#include <hip/hip_bf16.h>
#include <hip/hip_fp16.h>

// Problem constants (match reference)
static constexpr int CH     = 128;   // IN_CH == HID
static constexpr int NCLS   = 32;
static constexpr int NGRAPH = 256;

// Bucketed CSR build: buckets are 512-node ranges (bucket = dst >> 9).
static constexpr int BSHIFT = 9;
static constexpr int BW     = 1 << BSHIFT;   // 512 nodes per bucket
static constexpr int MAXB   = 256;

typedef _Float16 half8 __attribute__((ext_vector_type(8)));
typedef float    f32x4 __attribute__((ext_vector_type(4)));

// ---------------------------------------------------------------------------
// 1) bucket histogram (LDS-aggregated)
// ---------------------------------------------------------------------------
__global__ __launch_bounds__(256) void k_hist(const int* __restrict__ dst,
                                              int* __restrict__ gbcnt, int E) {
  __shared__ int h[MAXB];
  int t = threadIdx.x;
  h[t] = 0;
  __syncthreads();
  for (int i = blockIdx.x * 256 + t; i < E; i += gridDim.x * 256)
    atomicAdd(&h[dst[i] >> BSHIFT], 1);
  __syncthreads();
  if (h[t]) atomicAdd(&gbcnt[t], h[t]);
}

// ---------------------------------------------------------------------------
// 2) scan bucket counts -> ebase[257]; init bucket cursors
// ---------------------------------------------------------------------------
__global__ __launch_bounds__(256) void k_bscan(const int* __restrict__ gbcnt,
                                               int* __restrict__ ebase,
                                               int* __restrict__ gcur) {
  __shared__ int s[MAXB];
  int t = threadIdx.x;
  int v0 = gbcnt[t];
  s[t] = v0;
  __syncthreads();
  for (int st = 1; st < MAXB; st <<= 1) {
    int v = (t >= st) ? s[t - st] : 0;
    __syncthreads();
    s[t] += v;
    __syncthreads();
  }
  int ex = s[t] - v0;
  ebase[t] = ex;
  gcur[t]  = ex;
  if (t == MAXB - 1) ebase[MAXB] = s[t];
}

// ---------------------------------------------------------------------------
// 3) scatter packed edges into bucket-ordered array.
//    pack = (dstlo << 17) | src   (dstlo < 512 -> 9 bits; src < 2^17)
// ---------------------------------------------------------------------------
__global__ __launch_bounds__(1024) void k_scatter(
    const int* __restrict__ src, const int* __restrict__ dst,
    int* __restrict__ gcur, int* __restrict__ ebuf, int E) {
  __shared__ int bcnt[MAXB];
  __shared__ int bbase[MAXB];
  int t = threadIdx.x;
  if (t < MAXB) bcnt[t] = 0;
  __syncthreads();
  int base = blockIdx.x * 8192;
  int s_[8], d_[8], r_[8];
  #pragma unroll
  for (int j = 0; j < 8; ++j) {
    int i = base + j * 1024 + t;
    if (i < E) {
      s_[j] = src[i];
      d_[j] = dst[i];
      r_[j] = atomicAdd(&bcnt[d_[j] >> BSHIFT], 1);
    }
  }
  __syncthreads();
  if (t < MAXB && bcnt[t]) bbase[t] = atomicAdd(&gcur[t], bcnt[t]);
  __syncthreads();
  #pragma unroll
  for (int j = 0; j < 8; ++j) {
    int i = base + j * 1024 + t;
    if (i < E) {
      int b = d_[j] >> BSHIFT;
      int p = ((d_[j] & (BW - 1)) << 17) | s_[j];
      ebuf[bbase[b] + r_[j]] = p;
    }
  }
}

// ---------------------------------------------------------------------------
// 4) per-bucket CSR build (packed edges)
// ---------------------------------------------------------------------------
__global__ __launch_bounds__(1024) void k_build(
    const int* __restrict__ ebuf, const int* __restrict__ ebase,
    int* __restrict__ offs, float* __restrict__ dinv,
    int* __restrict__ csr, int N, int E, int NBUCK) {
  __shared__ int sdeg[BW];
  __shared__ int sscan[BW];
  int b = blockIdx.x;
  int t = threadIdx.x;
  int lo = b << BSHIFT;
  int e0 = ebase[b], e1 = ebase[b + 1];

  if (t < BW) sdeg[t] = 0;
  __syncthreads();
  for (int e = e0 + t; e < e1; e += 1024)
    atomicAdd(&sdeg[ebuf[e] >> 17], 1);
  __syncthreads();
  if (t < BW) sscan[t] = sdeg[t];
  __syncthreads();
  for (int st = 1; st < BW; st <<= 1) {
    int v = (t < BW && t >= st) ? sscan[t - st] : 0;
    __syncthreads();
    if (t < BW) sscan[t] += v;
    __syncthreads();
  }
  if (t < BW) {
    int ex = e0 + sscan[t] - sdeg[t];
    int n = lo + t;
    if (n < N) {
      offs[n] = ex;
      dinv[n] = 1.0f / sqrtf((float)(sdeg[t] + 1));
    }
    sscan[t] = ex;
  }
  if (b == NBUCK - 1 && t == 0) offs[N] = E;
  __syncthreads();
  for (int e = e0 + t; e < e1; e += 1024) {
    int p = ebuf[e];
    int pos = atomicAdd(&sscan[p >> 17], 1);
    csr[pos] = p & 0x1FFFF;
  }
}

// ---------------------------------------------------------------------------
// 5) one-shot W1,W2 -> fp16 transpose: WhT[n][k] = W[k][n]
// ---------------------------------------------------------------------------
__global__ __launch_bounds__(256) void k_wt(const float* __restrict__ W1,
                                            const float* __restrict__ W2,
                                            _Float16* __restrict__ WhT1,
                                            _Float16* __restrict__ WhT2) {
  int i = blockIdx.x * 256 + threadIdx.x;   // grid 128 x 256 = 32768
  const float* W = (i < CH * CH) ? W1 : W2;
  _Float16* T   = (i < CH * CH) ? WhT1 : WhT2;
  int j = i & (CH * CH - 1);
  int k = j >> 7, n = j & 127;
  T[n * CH + k] = (_Float16)W[j];
}

// ---------------------------------------------------------------------------
// MFMA GEMM: 64-row tiles, 4 waves x 16 rows, K=128 single shot.
// As 17.4KB + Ws 34.8KB = 52.2KB LDS -> 3 blocks/CU (12 waves) so the
// fp32 A-stream has latency-hiding headroom. acc = 32 VGPR/lane.
// ---------------------------------------------------------------------------
__device__ __forceinline__ void stage_w(const _Float16* __restrict__ WhT,
                                        _Float16 (*Ws)[136], int tid) {
  // straight row-major copy of 128x128 halfs, 16B chunks, conflict-free
  #pragma unroll
  for (int l = 0; l < 8; ++l) {
    int idx = tid + l * 256;            // 0..2047 half8 chunks
    int n = idx >> 4, k8 = (idx & 15) << 3;
    *(half8*)&Ws[n][k8] = *(const half8*)(WhT + n * CH + k8);
  }
}

__device__ __forceinline__ void gemm_core64(
    const _Float16 (*As)[136], const _Float16 (*Ws)[136],
    const float* __restrict__ dinv, __half* __restrict__ C,
    int row0, int M, int tid) {
  int lane = tid & 63, wave = tid >> 6;
  int quad = lane >> 4, sub = lane & 15;
  int m0 = wave * 16;                   // this wave: rows m0..m0+15 (in tile)

  f32x4 acc[8];
  #pragma unroll
  for (int j = 0; j < 8; ++j) acc[j] = (f32x4){0.f, 0.f, 0.f, 0.f};

  #pragma unroll
  for (int kc = 0; kc < 4; ++kc) {
    int ko = kc * 32 + quad * 8;
    half8 a = *(const half8*)&As[m0 + sub][ko];
    #pragma unroll
    for (int nt = 0; nt < 8; ++nt) {
      half8 b = *(const half8*)&Ws[nt * 16 + sub][ko];
      acc[nt] = __builtin_amdgcn_mfma_f32_16x16x32_f16(a, b, acc[nt], 0, 0, 0);
    }
  }
  #pragma unroll
  for (int r = 0; r < 4; ++r) {
    int row = row0 + m0 + quad * 4 + r;
    if (row < M) {
      float d = dinv[row];
      #pragma unroll
      for (int nt = 0; nt < 8; ++nt) {
        int col = nt * 16 + sub;
        C[(size_t)row * CH + col] = __float2half(acc[nt][r] * d);
      }
    }
  }
}

// A input fp32 (layer 1: x)
__global__ __launch_bounds__(256) void k_gemm_f32(
    const float* __restrict__ A, const _Float16* __restrict__ WhT,
    const float* __restrict__ dinv, __half* __restrict__ C, int M) {
  __shared__ _Float16 As[64][136];
  __shared__ _Float16 Ws[128][136];
  int tid = threadIdx.x;
  int row0 = blockIdx.x * 64;
  // stage A: 64 rows x 128 cols fp32 -> fp16 (2048 float4 slots, 8/thread)
  #pragma unroll
  for (int l = 0; l < 8; ++l) {
    int idx = tid + l * 256;
    int r = idx >> 5, c4 = (idx & 31) << 2;
    int rr = row0 + r; if (rr >= M) rr = M - 1;
    float4 v = *(const float4*)(A + (size_t)rr * CH + c4);
    As[r][c4 + 0] = (_Float16)v.x; As[r][c4 + 1] = (_Float16)v.y;
    As[r][c4 + 2] = (_Float16)v.z; As[r][c4 + 3] = (_Float16)v.w;
  }
  stage_w(WhT, Ws, tid);
  __syncthreads();
  gemm_core64(As, Ws, dinv, C, row0, M, tid);
}

// A input fp16 (layer 2: h)
__global__ __launch_bounds__(256) void k_gemm_f16(
    const _Float16* __restrict__ A, const _Float16* __restrict__ WhT,
    const float* __restrict__ dinv, __half* __restrict__ C, int M) {
  __shared__ _Float16 As[64][136];
  __shared__ _Float16 Ws[128][136];
  int tid = threadIdx.x;
  int row0 = blockIdx.x * 64;
  // stage A: 64 rows x 128 cols fp16 (1024 half8 chunks, 4/thread)
  #pragma unroll
  for (int l = 0; l < 4; ++l) {
    int idx = tid + l * 256;
    int r = idx >> 4, c8 = (idx & 15) << 3;
    int rr = row0 + r; if (rr >= M) rr = M - 1;
    *(half8*)&As[r][c8] = *(const half8*)(A + (size_t)rr * CH + c8);
  }
  stage_w(WhT, Ws, tid);
  __syncthreads();
  gemm_core64(As, Ws, dinv, C, row0, M, tid);
}

// ---------------------------------------------------------------------------
// Aggregation (pull, CSR): out fp16. Unroll 8 with two accumulator pairs
// for deeper MLP (gather is latency-bound on the L2-miss path).
// ---------------------------------------------------------------------------
__global__ __launch_bounds__(256) void k_agg(
    const __half* __restrict__ xs, const int* __restrict__ csr,
    const int* __restrict__ offs, const float* __restrict__ dinv,
    const float* __restrict__ bias, __half* __restrict__ out, int N) {
  int node = blockIdx.x * 4 + (threadIdx.x >> 6);
  int lane = threadIdx.x & 63;
  if (node >= N) return;
  int beg = offs[node], end = offs[node + 1];
  const __half2* base = (const __half2*)xs;
  float2 self = __half22float2(base[(size_t)node * 64 + lane]);
  float ax = self.x, ay = self.y;
  float bx = 0.f, by = 0.f;
  int e = beg;
  for (; e + 7 < end; e += 8) {
    int s0 = csr[e],     s1 = csr[e + 1], s2 = csr[e + 2], s3 = csr[e + 3];
    int s4 = csr[e + 4], s5 = csr[e + 5], s6 = csr[e + 6], s7 = csr[e + 7];
    float2 v0 = __half22float2(base[(size_t)s0 * 64 + lane]);
    float2 v1 = __half22float2(base[(size_t)s1 * 64 + lane]);
    float2 v2 = __half22float2(base[(size_t)s2 * 64 + lane]);
    float2 v3 = __half22float2(base[(size_t)s3 * 64 + lane]);
    float2 v4 = __half22float2(base[(size_t)s4 * 64 + lane]);
    float2 v5 = __half22float2(base[(size_t)s5 * 64 + lane]);
    float2 v6 = __half22float2(base[(size_t)s6 * 64 + lane]);
    float2 v7 = __half22float2(base[(size_t)s7 * 64 + lane]);
    ax += v0.x + v2.x + v4.x + v6.x;
    ay += v0.y + v2.y + v4.y + v6.y;
    bx += v1.x + v3.x + v5.x + v7.x;
    by += v1.y + v3.y + v5.y + v7.y;
  }
  for (; e < end; ++e) {
    int s = csr[e];
    float2 v = __half22float2(base[(size_t)s * 64 + lane]);
    ax += v.x; ay += v.y;
  }
  ax += bx; ay += by;
  float d = dinv[node];
  float rx = fmaf(ax, d, bias[2 * lane]);
  float ry = fmaf(ay, d, bias[2 * lane + 1]);
  ((__half2*)out)[(size_t)node * 64 + lane] =
      __floats2half2_rn(fmaxf(rx, 0.f), fmaxf(ry, 0.f));
}

// ---------------------------------------------------------------------------
// Pool + graph boundaries (batch sorted). Boundary pass costs ~1 iter/thread.
// ---------------------------------------------------------------------------
__global__ __launch_bounds__(128) void k_pool(
    const __half* __restrict__ h, const int* __restrict__ batch,
    float* __restrict__ gsum, int* __restrict__ gstart,
    int* __restrict__ gend, int N) {
  int ch = threadIdx.x;
  int n0 = blockIdx.x * 128;
  int n1 = n0 + 128; if (n1 > N) n1 = N;
  if (n0 >= N) return;
  // run boundaries (no atomics; gstart/gend pre-zeroed for empty graphs)
  for (int n = n0 + ch; n < n1; n += 128) {
    int g = batch[n];
    if (n == 0 || batch[n - 1] != g) gstart[g] = n;
    if (n == N - 1 || batch[n + 1] != g) gend[g] = n + 1;
  }
  float acc = 0.f;
  int curg = batch[n0];
  for (int n = n0; n < n1; ++n) {
    int g = batch[n];
    if (g != curg) {
      atomicAdd(&gsum[curg * CH + ch], acc);
      acc = 0.f; curg = g;
    }
    acc += __half2float(h[(size_t)n * CH + ch]);
  }
  atomicAdd(&gsum[curg * CH + ch], acc);
}

// ---------------------------------------------------------------------------
// FC
// ---------------------------------------------------------------------------
__global__ __launch_bounds__(64) void k_fc(
    const float* __restrict__ gsum, const int* __restrict__ gstart,
    const int* __restrict__ gend, const float* __restrict__ Wfc,
    const float* __restrict__ bfc, float* __restrict__ outp) {
  int g = blockIdx.x;
  int j = threadIdx.x;
  if (j >= NCLS) return;
  int cnt = gend[g] - gstart[g];
  float invc = 1.0f / fmaxf((float)cnt, 1.0f);
  float acc = 0.0f;
  for (int c = 0; c < CH; ++c)
    acc = fmaf(gsum[g * CH + c], Wfc[c * NCLS + j], acc);
  outp[g * NCLS + j] = fmaf(acc, invc, bfc[j]);
}

// ---------------------------------------------------------------------------
extern "C" void kernel_launch(void* const* d_in, const int* in_sizes, int n_in,
                              void* d_out, int out_size, void* d_ws, size_t ws_size,
                              hipStream_t stream) {
  const float* x    = (const float*)d_in[0];
  const int*   ei   = (const int*)d_in[1];
  const int*   batch= (const int*)d_in[2];
  const float* W1   = (const float*)d_in[3];
  const float* b1   = (const float*)d_in[4];
  const float* W2   = (const float*)d_in[5];
  const float* b2   = (const float*)d_in[6];
  const float* Wfc  = (const float*)d_in[7];
  const float* bfc  = (const float*)d_in[8];
  float* outp = (float*)d_out;

  const int N = in_sizes[0] / CH;       // 100000
  const int E = in_sizes[1] / 2;        // 3200000
  const int* src = ei;
  const int* dst = ei + E;
  const int NBUCK = (N + BW - 1) >> BSHIFT;   // 196

  // Workspace carve (256B aligned). The first four buffers are contiguous
  // and zero-initialized with ONE memset (sizes are multiples of 256B).
  char* w = (char*)d_ws;
  size_t o = 0;
  auto carve = [&](size_t bytes) -> void* {
    o = (o + 255) & ~(size_t)255;
    void* p = w + o;
    o += bytes;
    return p;
  };
  int*      gbcnt  = (int*)     carve(MAXB * 4);                 // zeroed
  float*    gsum   = (float*)   carve((size_t)NGRAPH * CH * 4);  // zeroed
  int*      gstart = (int*)     carve((size_t)NGRAPH * 4);       // zeroed
  int*      gend   = (int*)     carve((size_t)NGRAPH * 4);       // zeroed
  size_t zbytes = o;
  int*      offs   = (int*)     carve((size_t)(N + 1) * 4);
  int*      ebase  = (int*)     carve((MAXB + 1) * 4);
  int*      gcur   = (int*)     carve(MAXB * 4);
  int*      csr    = (int*)     carve((size_t)E * 4);
  float*    dinv   = (float*)   carve((size_t)N * 4);
  _Float16* WhT1   = (_Float16*)carve((size_t)CH * CH * 2);
  _Float16* WhT2   = (_Float16*)carve((size_t)CH * CH * 2);
  __half*   xsbuf  = (__half*)  carve((size_t)N * CH * 2);  // fp16 gather buffer
  __half*   hbuf   = (__half*)  carve((size_t)N * CH * 2);  // fp16 h
  (void)ws_size;

  // ebuf (packed edges) aliases hbuf: needs E*4 = 12.8MB <= 25.6MB
  int* ebuf = (int*)hbuf;

  (void)hipMemsetAsync(gbcnt, 0, zbytes, stream);

  // CSR build (bucketed counting sort) + weight transposes
  k_wt     <<<128, 256, 0, stream>>>(W1, W2, WhT1, WhT2);
  k_hist   <<<512, 256, 0, stream>>>(dst, gbcnt, E);
  k_bscan  <<<1, MAXB, 0, stream>>>(gbcnt, ebase, gcur);
  k_scatter<<<(E + 8191) / 8192, 1024, 0, stream>>>(src, dst, gcur, ebuf, E);
  k_build  <<<NBUCK, 1024, 0, stream>>>(ebuf, ebase, offs, dinv, csr, N, E, NBUCK);

  const int GB64 = (N + 63) / 64;
  const int GB   = (N + 127) / 128;
  const int AB   = (N + 3) / 4;

  // Layer 1: xs = fp16((x@W1)*dinv) ; h = fp16(relu(agg(xs)*dinv + b1))
  k_gemm_f32<<<GB64, 256, 0, stream>>>(x, WhT1, dinv, xsbuf, N);
  k_agg<<<AB, 256, 0, stream>>>(xsbuf, csr, offs, dinv, b1, hbuf, N);
  // Layer 2
  k_gemm_f16<<<GB64, 256, 0, stream>>>((const _Float16*)hbuf, WhT2, dinv, xsbuf, N);
  k_agg<<<AB, 256, 0, stream>>>(xsbuf, csr, offs, dinv, b2, hbuf, N);

  // Pool (+ boundaries) + FC
  k_pool<<<GB, 128, 0, stream>>>(hbuf, batch, gsum, gstart, gend, N);
  k_fc<<<NGRAPH, 64, 0, stream>>>(gsum, gstart, gend, Wfc, bfc, outp);
  (void)out_size; (void)n_in;
}

// Round 11
// 465.962 us; speedup vs baseline: 1.0971x; 1.0209x over previous
//
#include <hip/hip_runtime.h>
#include <hip/hip_bf16.h>
#include <hip/hip_fp16.h>

// Problem constants (match reference)
static constexpr int CH     = 128;   // IN_CH == HID
static constexpr int NCLS   = 32;
static constexpr int NGRAPH = 256;

// Bucketed CSR build: buckets are 512-node ranges (bucket = dst >> 9).
static constexpr int BSHIFT = 9;
static constexpr int BW     = 1 << BSHIFT;   // 512 nodes per bucket
static constexpr int MAXB   = 256;

typedef _Float16 half8 __attribute__((ext_vector_type(8)));
typedef _Float16 half4 __attribute__((ext_vector_type(4)));
typedef float    f32x4 __attribute__((ext_vector_type(4)));

// ---------------------------------------------------------------------------
// 1) bucket histogram (LDS-aggregated)
// ---------------------------------------------------------------------------
__global__ __launch_bounds__(256) void k_hist(const int* __restrict__ dst,
                                              int* __restrict__ gbcnt, int E) {
  __shared__ int h[MAXB];
  int t = threadIdx.x;
  h[t] = 0;
  __syncthreads();
  for (int i = blockIdx.x * 256 + t; i < E; i += gridDim.x * 256)
    atomicAdd(&h[dst[i] >> BSHIFT], 1);
  __syncthreads();
  if (h[t]) atomicAdd(&gbcnt[t], h[t]);
}

// ---------------------------------------------------------------------------
// 2) block 0: scan bucket counts -> ebase[257]; init cursors.
//    blocks 1..128: W1,W2 -> fp16 transpose (merged to save a dispatch).
// ---------------------------------------------------------------------------
__global__ __launch_bounds__(256) void k_bscan_wt(
    const int* __restrict__ gbcnt, int* __restrict__ ebase,
    int* __restrict__ gcur, const float* __restrict__ W1,
    const float* __restrict__ W2, _Float16* __restrict__ WhT1,
    _Float16* __restrict__ WhT2) {
  int t = threadIdx.x;
  if (blockIdx.x > 0) {
    int i = (blockIdx.x - 1) * 256 + t;       // 0..32767
    const float* W = (i < CH * CH) ? W1 : W2;
    _Float16* T   = (i < CH * CH) ? WhT1 : WhT2;
    int j = i & (CH * CH - 1);
    int k = j >> 7, n = j & 127;
    T[n * CH + k] = (_Float16)W[j];
    return;
  }
  __shared__ int s[MAXB];
  int v0 = gbcnt[t];
  s[t] = v0;
  __syncthreads();
  for (int st = 1; st < MAXB; st <<= 1) {
    int v = (t >= st) ? s[t - st] : 0;
    __syncthreads();
    s[t] += v;
    __syncthreads();
  }
  int ex = s[t] - v0;
  ebase[t] = ex;
  gcur[t]  = ex;
  if (t == MAXB - 1) ebase[MAXB] = s[t];
}

// ---------------------------------------------------------------------------
// 3) scatter packed edges into bucket-ordered array.
//    pack = (dstlo << 17) | src   (dstlo < 512 -> 9 bits; src < 2^17)
// ---------------------------------------------------------------------------
__global__ __launch_bounds__(1024) void k_scatter(
    const int* __restrict__ src, const int* __restrict__ dst,
    int* __restrict__ gcur, int* __restrict__ ebuf, int E) {
  __shared__ int bcnt[MAXB];
  __shared__ int bbase[MAXB];
  int t = threadIdx.x;
  if (t < MAXB) bcnt[t] = 0;
  __syncthreads();
  int base = blockIdx.x * 8192;
  int s_[8], d_[8], r_[8];
  #pragma unroll
  for (int j = 0; j < 8; ++j) {
    int i = base + j * 1024 + t;
    if (i < E) {
      s_[j] = src[i];
      d_[j] = dst[i];
      r_[j] = atomicAdd(&bcnt[d_[j] >> BSHIFT], 1);
    }
  }
  __syncthreads();
  if (t < MAXB && bcnt[t]) bbase[t] = atomicAdd(&gcur[t], bcnt[t]);
  __syncthreads();
  #pragma unroll
  for (int j = 0; j < 8; ++j) {
    int i = base + j * 1024 + t;
    if (i < E) {
      int b = d_[j] >> BSHIFT;
      int p = ((d_[j] & (BW - 1)) << 17) | s_[j];
      ebuf[bbase[b] + r_[j]] = p;
    }
  }
}

// ---------------------------------------------------------------------------
// 4) per-bucket CSR build (packed edges)
// ---------------------------------------------------------------------------
__global__ __launch_bounds__(1024) void k_build(
    const int* __restrict__ ebuf, const int* __restrict__ ebase,
    int* __restrict__ offs, float* __restrict__ dinv,
    int* __restrict__ csr, int N, int E, int NBUCK) {
  __shared__ int sdeg[BW];
  __shared__ int sscan[BW];
  int b = blockIdx.x;
  int t = threadIdx.x;
  int lo = b << BSHIFT;
  int e0 = ebase[b], e1 = ebase[b + 1];

  if (t < BW) sdeg[t] = 0;
  __syncthreads();
  for (int e = e0 + t; e < e1; e += 1024)
    atomicAdd(&sdeg[ebuf[e] >> 17], 1);
  __syncthreads();
  if (t < BW) sscan[t] = sdeg[t];
  __syncthreads();
  for (int st = 1; st < BW; st <<= 1) {
    int v = (t < BW && t >= st) ? sscan[t - st] : 0;
    __syncthreads();
    if (t < BW) sscan[t] += v;
    __syncthreads();
  }
  if (t < BW) {
    int ex = e0 + sscan[t] - sdeg[t];
    int n = lo + t;
    if (n < N) {
      offs[n] = ex;
      dinv[n] = 1.0f / sqrtf((float)(sdeg[t] + 1));
    }
    sscan[t] = ex;
  }
  if (b == NBUCK - 1 && t == 0) offs[N] = E;
  __syncthreads();
  for (int e = e0 + t; e < e1; e += 1024) {
    int p = ebuf[e];
    int pos = atomicAdd(&sscan[p >> 17], 1);
    csr[pos] = p & 0x1FFFF;
  }
}

// ---------------------------------------------------------------------------
// MFMA GEMM: 64-row tiles, 4 waves x 16 rows, K=128 single shot.
// As 17.4KB + Ws 34.8KB = 52.2KB LDS -> 3 blocks/CU (12 waves).
// ---------------------------------------------------------------------------
__device__ __forceinline__ void stage_w(const _Float16* __restrict__ WhT,
                                        _Float16 (*Ws)[136], int tid) {
  #pragma unroll
  for (int l = 0; l < 8; ++l) {
    int idx = tid + l * 256;            // 0..2047 half8 chunks
    int n = idx >> 4, k8 = (idx & 15) << 3;
    *(half8*)&Ws[n][k8] = *(const half8*)(WhT + n * CH + k8);
  }
}

__device__ __forceinline__ void gemm_core64(
    const _Float16 (*As)[136], const _Float16 (*Ws)[136],
    const float* __restrict__ dinv, __half* __restrict__ C,
    int row0, int M, int tid) {
  int lane = tid & 63, wave = tid >> 6;
  int quad = lane >> 4, sub = lane & 15;
  int m0 = wave * 16;                   // this wave: rows m0..m0+15 (in tile)

  f32x4 acc[8];
  #pragma unroll
  for (int j = 0; j < 8; ++j) acc[j] = (f32x4){0.f, 0.f, 0.f, 0.f};

  #pragma unroll
  for (int kc = 0; kc < 4; ++kc) {
    int ko = kc * 32 + quad * 8;
    half8 a = *(const half8*)&As[m0 + sub][ko];
    #pragma unroll
    for (int nt = 0; nt < 8; ++nt) {
      half8 b = *(const half8*)&Ws[nt * 16 + sub][ko];
      acc[nt] = __builtin_amdgcn_mfma_f32_16x16x32_f16(a, b, acc[nt], 0, 0, 0);
    }
  }
  #pragma unroll
  for (int r = 0; r < 4; ++r) {
    int row = row0 + m0 + quad * 4 + r;
    if (row < M) {
      float d = dinv[row];
      #pragma unroll
      for (int nt = 0; nt < 8; ++nt) {
        int col = nt * 16 + sub;
        C[(size_t)row * CH + col] = __float2half(acc[nt][r] * d);
      }
    }
  }
}

// A input fp32 (layer 1: x) — packed half4 LDS stores (8B, not 4x u16)
__global__ __launch_bounds__(256) void k_gemm_f32(
    const float* __restrict__ A, const _Float16* __restrict__ WhT,
    const float* __restrict__ dinv, __half* __restrict__ C, int M) {
  __shared__ _Float16 As[64][136];
  __shared__ _Float16 Ws[128][136];
  int tid = threadIdx.x;
  int row0 = blockIdx.x * 64;
  #pragma unroll
  for (int l = 0; l < 8; ++l) {
    int idx = tid + l * 256;
    int r = idx >> 5, c4 = (idx & 31) << 2;
    int rr = row0 + r; if (rr >= M) rr = M - 1;
    float4 v = *(const float4*)(A + (size_t)rr * CH + c4);
    half4 hv = { (_Float16)v.x, (_Float16)v.y, (_Float16)v.z, (_Float16)v.w };
    *(half4*)&As[r][c4] = hv;           // one b64 LDS store
  }
  stage_w(WhT, Ws, tid);
  __syncthreads();
  gemm_core64(As, Ws, dinv, C, row0, M, tid);
}

// A input fp16 (layer 2: h)
__global__ __launch_bounds__(256) void k_gemm_f16(
    const _Float16* __restrict__ A, const _Float16* __restrict__ WhT,
    const float* __restrict__ dinv, __half* __restrict__ C, int M) {
  __shared__ _Float16 As[64][136];
  __shared__ _Float16 Ws[128][136];
  int tid = threadIdx.x;
  int row0 = blockIdx.x * 64;
  #pragma unroll
  for (int l = 0; l < 4; ++l) {
    int idx = tid + l * 256;
    int r = idx >> 4, c8 = (idx & 15) << 3;
    int rr = row0 + r; if (rr >= M) rr = M - 1;
    *(half8*)&As[r][c8] = *(const half8*)(A + (size_t)rr * CH + c8);
  }
  stage_w(WhT, Ws, tid);
  __syncthreads();
  gemm_core64(As, Ws, dinv, C, row0, M, tid);
}

// ---------------------------------------------------------------------------
// Aggregation (pull, CSR): out fp16. Unroll cascade 16/8/1 (gather is
// bound by HBM efficiency on random 256B requests; MLP depth helps).
// ---------------------------------------------------------------------------
__global__ __launch_bounds__(256) void k_agg(
    const __half* __restrict__ xs, const int* __restrict__ csr,
    const int* __restrict__ offs, const float* __restrict__ dinv,
    const float* __restrict__ bias, __half* __restrict__ out, int N) {
  int node = blockIdx.x * 4 + (threadIdx.x >> 6);
  int lane = threadIdx.x & 63;
  if (node >= N) return;
  int beg = offs[node], end = offs[node + 1];
  const __half2* base = (const __half2*)xs;
  float2 self = __half22float2(base[(size_t)node * 64 + lane]);
  float ax = self.x, ay = self.y;
  float bx = 0.f, by = 0.f;
  int e = beg;
  for (; e + 15 < end; e += 16) {
    int s[16];
    #pragma unroll
    for (int j = 0; j < 16; ++j) s[j] = csr[e + j];
    float2 v[16];
    #pragma unroll
    for (int j = 0; j < 16; ++j)
      v[j] = __half22float2(base[(size_t)s[j] * 64 + lane]);
    #pragma unroll
    for (int j = 0; j < 16; j += 4) {
      ax += v[j].x + v[j + 2].x;  ay += v[j].y + v[j + 2].y;
      bx += v[j + 1].x + v[j + 3].x;  by += v[j + 1].y + v[j + 3].y;
    }
  }
  for (; e + 7 < end; e += 8) {
    int s[8];
    #pragma unroll
    for (int j = 0; j < 8; ++j) s[j] = csr[e + j];
    float2 v[8];
    #pragma unroll
    for (int j = 0; j < 8; ++j)
      v[j] = __half22float2(base[(size_t)s[j] * 64 + lane]);
    #pragma unroll
    for (int j = 0; j < 8; j += 4) {
      ax += v[j].x + v[j + 2].x;  ay += v[j].y + v[j + 2].y;
      bx += v[j + 1].x + v[j + 3].x;  by += v[j + 1].y + v[j + 3].y;
    }
  }
  for (; e < end; ++e) {
    int s = csr[e];
    float2 v = __half22float2(base[(size_t)s * 64 + lane]);
    ax += v.x; ay += v.y;
  }
  ax += bx; ay += by;
  float d = dinv[node];
  float rx = fmaf(ax, d, bias[2 * lane]);
  float ry = fmaf(ay, d, bias[2 * lane + 1]);
  ((__half2*)out)[(size_t)node * 64 + lane] =
      __floats2half2_rn(fmaxf(rx, 0.f), fmaxf(ry, 0.f));
}

// ---------------------------------------------------------------------------
// Pool + graph boundaries (batch sorted). Boundary pass costs ~1 iter/thread.
// ---------------------------------------------------------------------------
__global__ __launch_bounds__(128) void k_pool(
    const __half* __restrict__ h, const int* __restrict__ batch,
    float* __restrict__ gsum, int* __restrict__ gstart,
    int* __restrict__ gend, int N) {
  int ch = threadIdx.x;
  int n0 = blockIdx.x * 128;
  int n1 = n0 + 128; if (n1 > N) n1 = N;
  if (n0 >= N) return;
  // run boundaries (no atomics; gstart/gend pre-zeroed for empty graphs)
  for (int n = n0 + ch; n < n1; n += 128) {
    int g = batch[n];
    if (n == 0 || batch[n - 1] != g) gstart[g] = n;
    if (n == N - 1 || batch[n + 1] != g) gend[g] = n + 1;
  }
  float acc = 0.f;
  int curg = batch[n0];
  for (int n = n0; n < n1; ++n) {
    int g = batch[n];
    if (g != curg) {
      atomicAdd(&gsum[curg * CH + ch], acc);
      acc = 0.f; curg = g;
    }
    acc += __half2float(h[(size_t)n * CH + ch]);
  }
  atomicAdd(&gsum[curg * CH + ch], acc);
}

// ---------------------------------------------------------------------------
// FC
// ---------------------------------------------------------------------------
__global__ __launch_bounds__(64) void k_fc(
    const float* __restrict__ gsum, const int* __restrict__ gstart,
    const int* __restrict__ gend, const float* __restrict__ Wfc,
    const float* __restrict__ bfc, float* __restrict__ outp) {
  int g = blockIdx.x;
  int j = threadIdx.x;
  if (j >= NCLS) return;
  int cnt = gend[g] - gstart[g];
  float invc = 1.0f / fmaxf((float)cnt, 1.0f);
  float acc = 0.0f;
  for (int c = 0; c < CH; ++c)
    acc = fmaf(gsum[g * CH + c], Wfc[c * NCLS + j], acc);
  outp[g * NCLS + j] = fmaf(acc, invc, bfc[j]);
}

// ---------------------------------------------------------------------------
extern "C" void kernel_launch(void* const* d_in, const int* in_sizes, int n_in,
                              void* d_out, int out_size, void* d_ws, size_t ws_size,
                              hipStream_t stream) {
  const float* x    = (const float*)d_in[0];
  const int*   ei   = (const int*)d_in[1];
  const int*   batch= (const int*)d_in[2];
  const float* W1   = (const float*)d_in[3];
  const float* b1   = (const float*)d_in[4];
  const float* W2   = (const float*)d_in[5];
  const float* b2   = (const float*)d_in[6];
  const float* Wfc  = (const float*)d_in[7];
  const float* bfc  = (const float*)d_in[8];
  float* outp = (float*)d_out;

  const int N = in_sizes[0] / CH;       // 100000
  const int E = in_sizes[1] / 2;        // 3200000
  const int* src = ei;
  const int* dst = ei + E;
  const int NBUCK = (N + BW - 1) >> BSHIFT;   // 196

  // Workspace carve (256B aligned). The first four buffers are contiguous
  // and zero-initialized with ONE memset (sizes are multiples of 256B).
  char* w = (char*)d_ws;
  size_t o = 0;
  auto carve = [&](size_t bytes) -> void* {
    o = (o + 255) & ~(size_t)255;
    void* p = w + o;
    o += bytes;
    return p;
  };
  int*      gbcnt  = (int*)     carve(MAXB * 4);                 // zeroed
  float*    gsum   = (float*)   carve((size_t)NGRAPH * CH * 4);  // zeroed
  int*      gstart = (int*)     carve((size_t)NGRAPH * 4);       // zeroed
  int*      gend   = (int*)     carve((size_t)NGRAPH * 4);       // zeroed
  size_t zbytes = o;
  int*      offs   = (int*)     carve((size_t)(N + 1) * 4);
  int*      ebase  = (int*)     carve((MAXB + 1) * 4);
  int*      gcur   = (int*)     carve(MAXB * 4);
  int*      csr    = (int*)     carve((size_t)E * 4);
  float*    dinv   = (float*)   carve((size_t)N * 4);
  _Float16* WhT1   = (_Float16*)carve((size_t)CH * CH * 2);
  _Float16* WhT2   = (_Float16*)carve((size_t)CH * CH * 2);
  __half*   xsbuf  = (__half*)  carve((size_t)N * CH * 2);  // fp16 gather buffer
  __half*   hbuf   = (__half*)  carve((size_t)N * CH * 2);  // fp16 h
  (void)ws_size;

  // ebuf (packed edges) aliases hbuf: needs E*4 = 12.8MB <= 25.6MB
  int* ebuf = (int*)hbuf;

  (void)hipMemsetAsync(gbcnt, 0, zbytes, stream);

  // CSR build (bucketed counting sort); wt merged into bscan grid
  k_hist    <<<512, 256, 0, stream>>>(dst, gbcnt, E);
  k_bscan_wt<<<129, 256, 0, stream>>>(gbcnt, ebase, gcur, W1, W2, WhT1, WhT2);
  k_scatter <<<(E + 8191) / 8192, 1024, 0, stream>>>(src, dst, gcur, ebuf, E);
  k_build   <<<NBUCK, 1024, 0, stream>>>(ebuf, ebase, offs, dinv, csr, N, E, NBUCK);

  const int GB64 = (N + 63) / 64;
  const int GB   = (N + 127) / 128;
  const int AB   = (N + 3) / 4;

  // Layer 1: xs = fp16((x@W1)*dinv) ; h = fp16(relu(agg(xs)*dinv + b1))
  k_gemm_f32<<<GB64, 256, 0, stream>>>(x, WhT1, dinv, xsbuf, N);
  k_agg<<<AB, 256, 0, stream>>>(xsbuf, csr, offs, dinv, b1, hbuf, N);
  // Layer 2
  k_gemm_f16<<<GB64, 256, 0, stream>>>((const _Float16*)hbuf, WhT2, dinv, xsbuf, N);
  k_agg<<<AB, 256, 0, stream>>>(xsbuf, csr, offs, dinv, b2, hbuf, N);

  // Pool (+ boundaries) + FC
  k_pool<<<GB, 128, 0, stream>>>(hbuf, batch, gsum, gstart, gend, N);
  k_fc<<<NGRAPH, 64, 0, stream>>>(gsum, gstart, gend, Wfc, bfc, outp);
  (void)out_size; (void)n_in;
}